// Round 5
// baseline (814.114 us; speedup 1.0000x reference)
//
#include <hip/hip_runtime.h>

#define D 64
#define NSLOT 7  // nodes per wave (grid sized so NSLOT*waves >= N)

// ---------------- CSR build ----------------

__global__ __launch_bounds__(256) void hist_kernel(const int* __restrict__ dst,
                                                   int* __restrict__ cnt, int E) {
  int e = blockIdx.x * 256 + threadIdx.x;
  if (e < E) atomicAdd(&cnt[dst[e]], 1);
}

__global__ __launch_bounds__(1024) void scan_partial_kernel(const int* __restrict__ cnt,
                                                            int* __restrict__ bsum, int N) {
  __shared__ int lds[1024];
  int i = blockIdx.x * 1024 + threadIdx.x;
  lds[threadIdx.x] = (i < N) ? cnt[i] : 0;
  __syncthreads();
  for (int off = 512; off > 0; off >>= 1) {
    if (threadIdx.x < off) lds[threadIdx.x] += lds[threadIdx.x + off];
    __syncthreads();
  }
  if (threadIdx.x == 0) bsum[blockIdx.x] = lds[0];
}

// exclusive scan of up to 64 block sums in one wave
__global__ void scan_bsum_kernel(int* __restrict__ bsum, int nb,
                                 int* __restrict__ row_ptr, int N, int E) {
  int tid = threadIdx.x;  // 64 threads
  int o = (tid < nb) ? bsum[tid] : 0;
  int v = o;
  for (int off = 1; off < 64; off <<= 1) {
    int t = __shfl_up(v, off, 64);
    if (tid >= off) v += t;
  }
  if (tid < nb) bsum[tid] = v - o;       // exclusive
  if (tid == 0) row_ptr[N] = E;          // total is always E
}

__global__ __launch_bounds__(1024) void scan_final_kernel(const int* __restrict__ cnt,
                                                          const int* __restrict__ bsum,
                                                          int* __restrict__ row_ptr,
                                                          int* __restrict__ cursor, int N) {
  __shared__ int lds[1024];
  int tid = threadIdx.x;
  int i = blockIdx.x * 1024 + tid;
  int v = (i < N) ? cnt[i] : 0;
  lds[tid] = v;
  __syncthreads();
  for (int off = 1; off < 1024; off <<= 1) {
    int t = (tid >= off) ? lds[tid - off] : 0;
    __syncthreads();
    lds[tid] += t;
    __syncthreads();
  }
  if (i < N) {
    int excl = bsum[blockIdx.x] + lds[tid] - v;
    row_ptr[i] = excl;
    cursor[i] = excl;
  }
}

__global__ __launch_bounds__(256) void scatter_kernel(const int* __restrict__ srcs,
                                                      const int* __restrict__ dst,
                                                      int* __restrict__ cursor,
                                                      int* __restrict__ csr_src, int E) {
  int e = blockIdx.x * 256 + threadIdx.x;
  if (e < E) {
    int p = atomicAdd(&cursor[dst[e]], 1);
    csr_src[p] = srcs[e];
  }
}

// ---------------- node MLP: R = relu(h@Wm1+bm1) (CHUNK-MAJOR [4][N][16]), HR = h@Wr+br ----------
// applies previous layer's folded BN inline from raw sums; bnS==null -> identity (layer 0)

__global__ __launch_bounds__(256, 4) void node_mlp_kernel(
    const float* __restrict__ hin, const float* __restrict__ bnS, const float* __restrict__ bnSS,
    const float* __restrict__ gammaL, const float* __restrict__ betaL,
    const float* __restrict__ W1, const float* __restrict__ b1,
    const float* __restrict__ W2, const float* __restrict__ b2,
    float* __restrict__ Rout, float* __restrict__ HRout, int N) {
  __shared__ float2 w12[D * D];  // [k][c] = {W1[k][c], W2[k][c]}
  __shared__ float hrow[32][D];
  const int tid = threadIdx.x;
  for (int i = tid; i < D * D; i += 256) w12[i] = make_float2(W1[i], W2[i]);
  const int c = tid & 63;
  const int w = tid >> 6;
  float sc = 1.f, sh = 0.f;
  if (bnS) {
    float invN = 1.f / (float)N;
    float mu = bnS[c] * invN;
    float var = bnSS[c] * invN - mu * mu;
    float s = gammaL[c] * rsqrtf(var + 1e-5f);
    sc = s;
    sh = betaL[c] - mu * s;
  }
  const float bb1 = b1[c], bb2 = b2[c];
  const size_t chunkBase = (size_t)(c >> 4) * N * 16;
  const int cw = c & 15;
  const int ntiles = (N + 31) >> 5;
  for (int t = blockIdx.x; t < ntiles; t += gridDim.x) {
    const int base = t * 32;
    __syncthreads();
#pragma unroll
    for (int j = 0; j < 8; ++j) {
      int r = 4 * j + w;
      int row = base + r;
      float v = (row < N) ? hin[(size_t)row * D + c] : 0.f;
      hrow[r][c] = v * sc + sh;
    }
    __syncthreads();
    float a1[8], a2[8];
#pragma unroll
    for (int j = 0; j < 8; ++j) { a1[j] = bb1; a2[j] = bb2; }
    for (int k = 0; k < D; k += 4) {
      const float2 wa = w12[(k + 0) * D + c];
      const float2 wb = w12[(k + 1) * D + c];
      const float2 wc = w12[(k + 2) * D + c];
      const float2 wd = w12[(k + 3) * D + c];
#pragma unroll
      for (int j = 0; j < 8; ++j) {
        const float4 h4 = *(const float4*)&hrow[w * 8 + j][k];
        a1[j] += h4.x * wa.x + h4.y * wb.x + h4.z * wc.x + h4.w * wd.x;
        a2[j] += h4.x * wa.y + h4.y * wb.y + h4.z * wc.y + h4.w * wd.y;
      }
    }
#pragma unroll
    for (int j = 0; j < 8; ++j) {
      int row = base + w * 8 + j;
      if (row < N) {
        Rout[chunkBase + (size_t)row * 16 + cw] = fmaxf(a1[j], 0.f);
        HRout[(size_t)row * D + c] = a2[j];
      }
    }
  }
}

// ---------------- chunk-phased aggregation + Wm2 + root add + PReLU + BN sums ----------------
// chunk OUTERMOST so the 3.2MB R-slice stays L2-resident grid-wide; lanes = 4 edges x 16 ch;
// per-chunk partial Wm2 matmul folds into per-node register accumulator o[s].

__device__ __forceinline__ float lane_bcast(float v, int lane) {
  return __int_as_float(__builtin_amdgcn_readlane(__float_as_int(v), lane));
}

__global__ __launch_bounds__(256, 8) void agg_kernel(const int* __restrict__ row_ptr,
                                                     const int* __restrict__ csr_src,
                                                     const float* __restrict__ Rc,
                                                     const float* __restrict__ HRm,
                                                     const float* __restrict__ W2m,
                                                     const float* __restrict__ b2m,
                                                     const float* __restrict__ aconv,
                                                     float* __restrict__ hout,
                                                     float* __restrict__ bnsum,
                                                     float* __restrict__ bnsumsq, int N) {
  __shared__ float w2[D * D];
  __shared__ float red[4][D];
  __shared__ float red2[4][D];
  const int tid = threadIdx.x;
  const int c = tid & 63;
  const int w = tid >> 6;
  for (int i = tid; i < D * D; i += 256) w2[i] = W2m[i];
  const int wid = blockIdx.x * 4 + w;
  const int NW = gridDim.x * 4;
  const int g = c >> 4;    // edge slot 0..3
  const int ch = c & 15;   // channel within chunk
  float o[NSLOT];
#pragma unroll
  for (int s = 0; s < NSLOT; ++s) o[s] = 0.f;
  __syncthreads();
  for (int t = 0; t < 4; ++t) {
    const float* __restrict__ Rt = Rc + (size_t)t * N * 16;
    float accs[NSLOT];
#pragma unroll
    for (int s = 0; s < NSLOT; ++s) {
      accs[s] = 0.f;
      const int n = wid + s * NW;
      if (n < N) {
        const int e0 = row_ptr[n];
        const int e1 = row_ptr[n + 1];
        float a0 = 0.f, a1 = 0.f;
        for (int kb = e0; kb < e1; kb += 8) {
          const int ka = kb + g;
          const int kc = kb + 4 + g;
          if (ka < e1) a0 += Rt[(size_t)csr_src[ka] * 16 + ch];
          if (kc < e1) a1 += Rt[(size_t)csr_src[kc] * 16 + ch];
        }
        float acc = a0 + a1;
        acc += __shfl_xor(acc, 16, 64);
        acc += __shfl_xor(acc, 32, 64);
        accs[s] = acc;  // every lane: total for channel (lane&15) of chunk t
      }
    }
    // partial matmul: one LDS read of W2 row per j, applied to all slots
#pragma unroll
    for (int j = 0; j < 16; ++j) {
      const float wj = w2[(t * 16 + j) * D + c];
#pragma unroll
      for (int s = 0; s < NSLOT; ++s) o[s] += lane_bcast(accs[s], j) * wj;
    }
  }
  const float alpha = *aconv;
  const float bb = b2m[c];
  float psum = 0.f, psumsq = 0.f;
#pragma unroll
  for (int s = 0; s < NSLOT; ++s) {
    const int n = wid + s * NW;
    if (n < N) {
      const float deg = (float)(row_ptr[n + 1] - row_ptr[n]);
      const float v = o[s] + bb * deg + HRm[(size_t)n * D + c];
      const float h2 = (v >= 0.f) ? v : alpha * v;
      hout[(size_t)n * D + c] = h2;
      psum += h2;
      psumsq += h2 * h2;
    }
  }
  red[w][c] = psum;
  red2[w][c] = psumsq;
  __syncthreads();
  if (w == 0) {
    float s = red[0][c] + red[1][c] + red[2][c] + red[3][c];
    float ss = red2[0][c] + red2[1][c] + red2[2][c] + red2[3][c];
    atomicAdd(&bnsum[c], s);
    atomicAdd(&bnsumsq[c], ss);
  }
}

// ---------------- pooling (sorted batch, binary search) + MLP head ----------------

__global__ __launch_bounds__(256) void pool_head_kernel(
    const float* __restrict__ h, const float* __restrict__ bnS, const float* __restrict__ bnSS,
    const float* __restrict__ gammaL, const float* __restrict__ betaL,
    const int* __restrict__ batch, const float* __restrict__ Wh1, const float* __restrict__ bh1,
    const float* __restrict__ Wh2, const float* __restrict__ bh2,
    const float* __restrict__ ahead, float* __restrict__ out, int N) {
  const int g = blockIdx.x;
  const int tid = threadIdx.x;
  const int c = tid & 63;
  const int w = tid >> 6;
  float sc, sh;
  {
    float invN = 1.f / (float)N;
    float mu = bnS[c] * invN;
    float var = bnSS[c] * invN - mu * mu;
    float s = gammaL[c] * rsqrtf(var + 1e-5f);
    sc = s;
    sh = betaL[c] - mu * s;
  }
  int s0, s1;
  {
    int lo = 0, hi = N;
    while (lo < hi) { int mid = (lo + hi) >> 1; if (batch[mid] < g) lo = mid + 1; else hi = mid; }
    s0 = lo;
    lo = s0; hi = N;
    while (lo < hi) { int mid = (lo + hi) >> 1; if (batch[mid] < g + 1) lo = mid + 1; else hi = mid; }
    s1 = lo;
  }
  float sum = 0.f;
  for (int r = s0 + w; r < s1; r += 4) sum += h[(size_t)r * D + c] * sc + sh;
  __shared__ float red[4][D];
  __shared__ float mean[D];
  red[w][c] = sum;
  __syncthreads();
  if (tid < D) {
    float cnt = (float)(s1 - s0);
    mean[c] = (red[0][c] + red[1][c] + red[2][c] + red[3][c]) / fmaxf(cnt, 1.0f);
  }
  __syncthreads();
  if (tid < D) {
    int j = tid;
    float a = bh1[j];
#pragma unroll
    for (int k = 0; k < D; ++k) a += mean[k] * Wh1[k * D + j];
    float al = *ahead;
    float v = (a >= 0.f) ? a : al * a;
    float pval = v * Wh2[j];
    for (int off = 32; off > 0; off >>= 1) pval += __shfl_down(pval, off, 64);
    if (j == 0) out[g] = pval + bh2[0];
  }
}

// ---------------- host ----------------

extern "C" void kernel_launch(void* const* d_in, const int* in_sizes, int n_in,
                              void* d_out, int out_size, void* d_ws, size_t ws_size,
                              hipStream_t stream) {
  const float* x = (const float*)d_in[0];
  const int* ei = (const int*)d_in[1];
  const int* batch = (const int*)d_in[2];
  const float* Wm1 = (const float*)d_in[3];
  const float* bm1 = (const float*)d_in[4];
  const float* Wm2 = (const float*)d_in[5];
  const float* bm2 = (const float*)d_in[6];
  const float* Wr = (const float*)d_in[7];
  const float* br = (const float*)d_in[8];
  const float* aconv = (const float*)d_in[9];
  const float* gamma = (const float*)d_in[10];
  const float* beta = (const float*)d_in[11];
  const float* Wh1 = (const float*)d_in[12];
  const float* bh1 = (const float*)d_in[13];
  const float* Wh2 = (const float*)d_in[14];
  const float* bh2 = (const float*)d_in[15];
  const float* ahead = (const float*)d_in[16];

  const int N = in_sizes[0] / D;
  const int E = in_sizes[1] / 2;
  const int L = in_sizes[3] / (D * D);
  const int G = out_size;

  const int* srcs = ei;
  const int* dsts = ei + E;

  char* p = (char*)d_ws;
  auto alloc = [&](size_t bytes) {
    char* r = p;
    p += (bytes + 255) & ~(size_t)255;
    return r;
  };
  int* row_ptr = (int*)alloc((size_t)(N + 1) * 4);
  int* cursor = (int*)alloc((size_t)N * 4);
  int* bsum = (int*)alloc(64 * 4);
  int* csr_src = (int*)alloc((size_t)E * 4);
  float* Rbuf = (float*)alloc((size_t)N * D * 4);   // chunk-major [4][N][16]
  float* HRbuf = (float*)alloc((size_t)N * D * 4);
  float* hbuf = (float*)alloc((size_t)N * D * 4);
  float* bnsum = (float*)alloc((size_t)L * D * 4 * 2);
  float* bnsumsq = bnsum + (size_t)L * D;

  hipMemsetAsync(row_ptr, 0, (size_t)((char*)(cursor + N) - (char*)row_ptr), stream);
  hipMemsetAsync(bnsum, 0, (size_t)L * D * 4 * 2, stream);

  // CSR build
  const int nb = (N + 1023) / 1024;
  hist_kernel<<<(E + 255) / 256, 256, 0, stream>>>(dsts, cursor, E);
  scan_partial_kernel<<<nb, 1024, 0, stream>>>(cursor, bsum, N);
  scan_bsum_kernel<<<1, 64, 0, stream>>>(bsum, nb, row_ptr, N, E);
  scan_final_kernel<<<nb, 1024, 0, stream>>>(cursor, bsum, row_ptr, cursor, N);
  scatter_kernel<<<(E + 255) / 256, 256, 0, stream>>>(srcs, dsts, cursor, csr_src, E);

  const int ntiles = (N + 31) / 32;
  const int agg_blocks = (N + NSLOT * 4 - 1) / (NSLOT * 4);  // all co-resident at 8/CU

  const float* hin = x;
  const float* bnS = nullptr;
  const float* bnSS = nullptr;
  const float* gmL = nullptr;
  const float* btL = nullptr;
  for (int l = 0; l < L; ++l) {
    node_mlp_kernel<<<ntiles, 256, 0, stream>>>(hin, bnS, bnSS, gmL, btL,
                                                Wm1 + (size_t)l * D * D, bm1 + l * D,
                                                Wr + (size_t)l * D * D, br + l * D,
                                                Rbuf, HRbuf, N);
    agg_kernel<<<agg_blocks, 256, 0, stream>>>(row_ptr, csr_src, Rbuf, HRbuf,
                                               Wm2 + (size_t)l * D * D, bm2 + l * D, aconv + l,
                                               hbuf, bnsum + l * D, bnsumsq + l * D, N);
    hin = hbuf;
    bnS = bnsum + l * D;
    bnSS = bnsumsq + l * D;
    gmL = gamma + l * D;
    btL = beta + l * D;
  }

  pool_head_kernel<<<G, 256, 0, stream>>>(hbuf, bnS, bnSS, gmL, btL, batch,
                                          Wh1, bh1, Wh2, bh2, ahead, (float*)d_out, N);
}

// Round 6
// 602.798 us; speedup vs baseline: 1.3506x; 1.3506x over previous
//
#include <hip/hip_runtime.h>

#define D 64

// ---------------- CSR build ----------------

__global__ __launch_bounds__(256) void hist_kernel(const int* __restrict__ dst,
                                                   int* __restrict__ cnt, int E) {
  int e = blockIdx.x * 256 + threadIdx.x;
  if (e < E) atomicAdd(&cnt[dst[e]], 1);
}

__global__ __launch_bounds__(1024) void scan_partial_kernel(const int* __restrict__ cnt,
                                                            int* __restrict__ bsum, int N) {
  __shared__ int lds[1024];
  int i = blockIdx.x * 1024 + threadIdx.x;
  lds[threadIdx.x] = (i < N) ? cnt[i] : 0;
  __syncthreads();
  for (int off = 512; off > 0; off >>= 1) {
    if (threadIdx.x < off) lds[threadIdx.x] += lds[threadIdx.x + off];
    __syncthreads();
  }
  if (threadIdx.x == 0) bsum[blockIdx.x] = lds[0];
}

// exclusive scan of up to 64 block sums in one wave
__global__ void scan_bsum_kernel(int* __restrict__ bsum, int nb,
                                 int* __restrict__ row_ptr, int N, int E) {
  int tid = threadIdx.x;  // 64 threads
  int o = (tid < nb) ? bsum[tid] : 0;
  int v = o;
  for (int off = 1; off < 64; off <<= 1) {
    int t = __shfl_up(v, off, 64);
    if (tid >= off) v += t;
  }
  if (tid < nb) bsum[tid] = v - o;       // exclusive
  if (tid == 0) row_ptr[N] = E;          // total is always E
}

__global__ __launch_bounds__(1024) void scan_final_kernel(const int* __restrict__ cnt,
                                                          const int* __restrict__ bsum,
                                                          int* __restrict__ row_ptr,
                                                          int* __restrict__ cursor, int N) {
  __shared__ int lds[1024];
  int tid = threadIdx.x;
  int i = blockIdx.x * 1024 + tid;
  int v = (i < N) ? cnt[i] : 0;
  lds[tid] = v;
  __syncthreads();
  for (int off = 1; off < 1024; off <<= 1) {
    int t = (tid >= off) ? lds[tid - off] : 0;
    __syncthreads();
    lds[tid] += t;
    __syncthreads();
  }
  if (i < N) {
    int excl = bsum[blockIdx.x] + lds[tid] - v;
    row_ptr[i] = excl;
    cursor[i] = excl;
  }
}

__global__ __launch_bounds__(256) void scatter_kernel(const int* __restrict__ srcs,
                                                      const int* __restrict__ dst,
                                                      int* __restrict__ cursor,
                                                      int* __restrict__ csr_src, int E) {
  int e = blockIdx.x * 256 + threadIdx.x;
  if (e < E) {
    int p = atomicAdd(&cursor[dst[e]], 1);
    csr_src[p] = srcs[e];
  }
}

// ---------------- node MLP: R = relu(h@Wm1+bm1) (row-major), HR = h@Wr+br ----------------
// applies previous layer's folded BN inline from raw sums; bnS==null -> identity (layer 0)

__global__ __launch_bounds__(256, 4) void node_mlp_kernel(
    const float* __restrict__ hin, const float* __restrict__ bnS, const float* __restrict__ bnSS,
    const float* __restrict__ gammaL, const float* __restrict__ betaL,
    const float* __restrict__ W1, const float* __restrict__ b1,
    const float* __restrict__ W2, const float* __restrict__ b2,
    float* __restrict__ Rout, float* __restrict__ HRout, int N) {
  __shared__ float2 w12[D * D];  // [k][c] = {W1[k][c], W2[k][c]}
  __shared__ float hrow[32][D];
  const int tid = threadIdx.x;
  for (int i = tid; i < D * D; i += 256) w12[i] = make_float2(W1[i], W2[i]);
  const int c = tid & 63;
  const int w = tid >> 6;
  float sc = 1.f, sh = 0.f;
  if (bnS) {
    float invN = 1.f / (float)N;
    float mu = bnS[c] * invN;
    float var = bnSS[c] * invN - mu * mu;
    float s = gammaL[c] * rsqrtf(var + 1e-5f);
    sc = s;
    sh = betaL[c] - mu * s;
  }
  const float bb1 = b1[c], bb2 = b2[c];
  const int ntiles = (N + 31) >> 5;
  for (int t = blockIdx.x; t < ntiles; t += gridDim.x) {
    const int base = t * 32;
    __syncthreads();
#pragma unroll
    for (int j = 0; j < 8; ++j) {
      int r = 4 * j + w;
      int row = base + r;
      float v = (row < N) ? hin[(size_t)row * D + c] : 0.f;
      hrow[r][c] = v * sc + sh;
    }
    __syncthreads();
    float a1[8], a2[8];
#pragma unroll
    for (int j = 0; j < 8; ++j) { a1[j] = bb1; a2[j] = bb2; }
    for (int k = 0; k < D; k += 4) {
      const float2 wa = w12[(k + 0) * D + c];
      const float2 wb = w12[(k + 1) * D + c];
      const float2 wc = w12[(k + 2) * D + c];
      const float2 wd = w12[(k + 3) * D + c];
#pragma unroll
      for (int j = 0; j < 8; ++j) {
        const float4 h4 = *(const float4*)&hrow[w * 8 + j][k];
        a1[j] += h4.x * wa.x + h4.y * wb.x + h4.z * wc.x + h4.w * wd.x;
        a2[j] += h4.x * wa.y + h4.y * wb.y + h4.z * wc.y + h4.w * wd.y;
      }
    }
#pragma unroll
    for (int j = 0; j < 8; ++j) {
      int row = base + w * 8 + j;
      if (row < N) {
        Rout[(size_t)row * D + c] = fmaxf(a1[j], 0.f);
        HRout[(size_t)row * D + c] = a2[j];
      }
    }
  }
}

// ---------------- aggregation + Wm2 + root add + PReLU + BN partial sums ----------------
// per node: ONE coalesced per-lane index load (lane j holds csr_src[e0+j]); gather addresses
// broadcast via v_readlane (SGPR/SALU address path); next node's indices prefetched under
// the current node's gathers+matmul. ~1-2 exposed latencies per node.

__device__ __forceinline__ float lane_bcast(float v, int lane) {
  return __int_as_float(__builtin_amdgcn_readlane(__float_as_int(v), lane));
}
__device__ __forceinline__ int lane_bcast_i(int v, int lane) {
  return __builtin_amdgcn_readlane(v, lane);
}

__global__ __launch_bounds__(256) void agg_kernel(const int* __restrict__ row_ptr,
                                                  const int* __restrict__ csr_src,
                                                  const float* __restrict__ Rm,
                                                  const float* __restrict__ HRm,
                                                  const float* __restrict__ W2m,
                                                  const float* __restrict__ b2m,
                                                  const float* __restrict__ aconv,
                                                  float* __restrict__ hout,
                                                  float* __restrict__ bnsum,
                                                  float* __restrict__ bnsumsq, int N) {
  __shared__ float w2[D * D];
  __shared__ float red[4][D];
  __shared__ float red2[4][D];
  const int tid = threadIdx.x;
  const int c = tid & 63;
  const int w = tid >> 6;
  for (int i = tid; i < D * D; i += 256) w2[i] = W2m[i];
  const float alpha = *aconv;
  const float bb = b2m[c];
  const int NW = gridDim.x * 4;
  float psum = 0.f, psumsq = 0.f;
  __syncthreads();

  int n = blockIdx.x * 4 + w;
  int e0 = 0, e1 = 0, idx = 0;
  if (n < N) {
    e0 = row_ptr[n];
    e1 = row_ptr[n + 1];
    int m = e1 - e0;
    if (m > 64) m = 64;
    if (m > 0) idx = csr_src[e0 + (c < m ? c : m - 1)];
  }
  while (n < N) {
    // ---- prefetch next node's extents + indices (hidden under gathers/matmul) ----
    const int n2 = n + NW;
    int e0n = 0, e1n = 0, idxn = 0;
    if (n2 < N) {
      e0n = row_ptr[n2];
      e1n = row_ptr[n2 + 1];
      int mn = e1n - e0n;
      if (mn > 64) mn = 64;
      if (mn > 0) idxn = csr_src[e0n + (c < mn ? c : mn - 1)];
    }
    // ---- gather current node ----
    const int deg = e1 - e0;
    float acc0 = 0.f, acc1 = 0.f, acc2 = 0.f, acc3 = 0.f;
    float acc4 = 0.f, acc5 = 0.f, acc6 = 0.f, acc7 = 0.f;
    int kb = 0;
    int curidx = idx;
    while (kb < deg) {
      int m = deg - kb;
      if (m > 64) m = 64;
      if (kb > 0) curidx = csr_src[e0 + kb + (c < m ? c : m - 1)];
      int j = 0;
      for (; j + 7 < m; j += 8) {
        const int s0 = lane_bcast_i(curidx, j + 0);
        const int s1 = lane_bcast_i(curidx, j + 1);
        const int s2 = lane_bcast_i(curidx, j + 2);
        const int s3 = lane_bcast_i(curidx, j + 3);
        const int s4 = lane_bcast_i(curidx, j + 4);
        const int s5 = lane_bcast_i(curidx, j + 5);
        const int s6 = lane_bcast_i(curidx, j + 6);
        const int s7 = lane_bcast_i(curidx, j + 7);
        acc0 += Rm[(size_t)s0 * D + c];
        acc1 += Rm[(size_t)s1 * D + c];
        acc2 += Rm[(size_t)s2 * D + c];
        acc3 += Rm[(size_t)s3 * D + c];
        acc4 += Rm[(size_t)s4 * D + c];
        acc5 += Rm[(size_t)s5 * D + c];
        acc6 += Rm[(size_t)s6 * D + c];
        acc7 += Rm[(size_t)s7 * D + c];
      }
      for (; j < m; ++j) acc0 += Rm[(size_t)lane_bcast_i(curidx, j) * D + c];
      kb += m;
    }
    const float aggv = ((acc0 + acc1) + (acc2 + acc3)) + ((acc4 + acc5) + (acc6 + acc7));
    // ---- Wm2 matmul + root + PReLU + BN ----
    const float degf = (float)deg;
    float o0 = bb * degf + HRm[(size_t)n * D + c];
    float o1 = 0.f, o2 = 0.f, o3 = 0.f;
#pragma unroll
    for (int kk = 0; kk < D; kk += 4) {
      o0 += lane_bcast(aggv, kk + 0) * w2[(kk + 0) * D + c];
      o1 += lane_bcast(aggv, kk + 1) * w2[(kk + 1) * D + c];
      o2 += lane_bcast(aggv, kk + 2) * w2[(kk + 2) * D + c];
      o3 += lane_bcast(aggv, kk + 3) * w2[(kk + 3) * D + c];
    }
    const float o = (o0 + o1) + (o2 + o3);
    const float h2 = (o >= 0.f) ? o : alpha * o;
    hout[(size_t)n * D + c] = h2;
    psum += h2;
    psumsq += h2 * h2;
    // ---- advance ----
    n = n2;
    e0 = e0n;
    e1 = e1n;
    idx = idxn;
  }
  red[w][c] = psum;
  red2[w][c] = psumsq;
  __syncthreads();
  if (w == 0) {
    float s = red[0][c] + red[1][c] + red[2][c] + red[3][c];
    float ss = red2[0][c] + red2[1][c] + red2[2][c] + red2[3][c];
    atomicAdd(&bnsum[c], s);
    atomicAdd(&bnsumsq[c], ss);
  }
}

// ---------------- pooling (sorted batch, binary search) + MLP head ----------------

__global__ __launch_bounds__(256) void pool_head_kernel(
    const float* __restrict__ h, const float* __restrict__ bnS, const float* __restrict__ bnSS,
    const float* __restrict__ gammaL, const float* __restrict__ betaL,
    const int* __restrict__ batch, const float* __restrict__ Wh1, const float* __restrict__ bh1,
    const float* __restrict__ Wh2, const float* __restrict__ bh2,
    const float* __restrict__ ahead, float* __restrict__ out, int N) {
  const int g = blockIdx.x;
  const int tid = threadIdx.x;
  const int c = tid & 63;
  const int w = tid >> 6;
  float sc, sh;
  {
    float invN = 1.f / (float)N;
    float mu = bnS[c] * invN;
    float var = bnSS[c] * invN - mu * mu;
    float s = gammaL[c] * rsqrtf(var + 1e-5f);
    sc = s;
    sh = betaL[c] - mu * s;
  }
  int s0, s1;
  {
    int lo = 0, hi = N;
    while (lo < hi) { int mid = (lo + hi) >> 1; if (batch[mid] < g) lo = mid + 1; else hi = mid; }
    s0 = lo;
    lo = s0; hi = N;
    while (lo < hi) { int mid = (lo + hi) >> 1; if (batch[mid] < g + 1) lo = mid + 1; else hi = mid; }
    s1 = lo;
  }
  float sum = 0.f;
  for (int r = s0 + w; r < s1; r += 4) sum += h[(size_t)r * D + c] * sc + sh;
  __shared__ float red[4][D];
  __shared__ float mean[D];
  red[w][c] = sum;
  __syncthreads();
  if (tid < D) {
    float cnt = (float)(s1 - s0);
    mean[c] = (red[0][c] + red[1][c] + red[2][c] + red[3][c]) / fmaxf(cnt, 1.0f);
  }
  __syncthreads();
  if (tid < D) {
    int j = tid;
    float a = bh1[j];
#pragma unroll
    for (int k = 0; k < D; ++k) a += mean[k] * Wh1[k * D + j];
    float al = *ahead;
    float v = (a >= 0.f) ? a : al * a;
    float pval = v * Wh2[j];
    for (int off = 32; off > 0; off >>= 1) pval += __shfl_down(pval, off, 64);
    if (j == 0) out[g] = pval + bh2[0];
  }
}

// ---------------- host ----------------

extern "C" void kernel_launch(void* const* d_in, const int* in_sizes, int n_in,
                              void* d_out, int out_size, void* d_ws, size_t ws_size,
                              hipStream_t stream) {
  const float* x = (const float*)d_in[0];
  const int* ei = (const int*)d_in[1];
  const int* batch = (const int*)d_in[2];
  const float* Wm1 = (const float*)d_in[3];
  const float* bm1 = (const float*)d_in[4];
  const float* Wm2 = (const float*)d_in[5];
  const float* bm2 = (const float*)d_in[6];
  const float* Wr = (const float*)d_in[7];
  const float* br = (const float*)d_in[8];
  const float* aconv = (const float*)d_in[9];
  const float* gamma = (const float*)d_in[10];
  const float* beta = (const float*)d_in[11];
  const float* Wh1 = (const float*)d_in[12];
  const float* bh1 = (const float*)d_in[13];
  const float* Wh2 = (const float*)d_in[14];
  const float* bh2 = (const float*)d_in[15];
  const float* ahead = (const float*)d_in[16];

  const int N = in_sizes[0] / D;
  const int E = in_sizes[1] / 2;
  const int L = in_sizes[3] / (D * D);
  const int G = out_size;

  const int* srcs = ei;
  const int* dsts = ei + E;

  char* p = (char*)d_ws;
  auto alloc = [&](size_t bytes) {
    char* r = p;
    p += (bytes + 255) & ~(size_t)255;
    return r;
  };
  int* row_ptr = (int*)alloc((size_t)(N + 1) * 4);
  int* cursor = (int*)alloc((size_t)N * 4);
  int* bsum = (int*)alloc(64 * 4);
  int* csr_src = (int*)alloc((size_t)E * 4);
  float* Rbuf = (float*)alloc((size_t)N * D * 4);
  float* HRbuf = (float*)alloc((size_t)N * D * 4);
  float* hbuf = (float*)alloc((size_t)N * D * 4);
  float* bnsum = (float*)alloc((size_t)L * D * 4 * 2);
  float* bnsumsq = bnsum + (size_t)L * D;

  hipMemsetAsync(row_ptr, 0, (size_t)((char*)(cursor + N) - (char*)row_ptr), stream);
  hipMemsetAsync(bnsum, 0, (size_t)L * D * 4 * 2, stream);

  // CSR build
  const int nb = (N + 1023) / 1024;
  hist_kernel<<<(E + 255) / 256, 256, 0, stream>>>(dsts, cursor, E);
  scan_partial_kernel<<<nb, 1024, 0, stream>>>(cursor, bsum, N);
  scan_bsum_kernel<<<1, 64, 0, stream>>>(bsum, nb, row_ptr, N, E);
  scan_final_kernel<<<nb, 1024, 0, stream>>>(cursor, bsum, row_ptr, cursor, N);
  scatter_kernel<<<(E + 255) / 256, 256, 0, stream>>>(srcs, dsts, cursor, csr_src, E);

  const int ntiles = (N + 31) / 32;

  const float* hin = x;
  const float* bnS = nullptr;
  const float* bnSS = nullptr;
  const float* gmL = nullptr;
  const float* btL = nullptr;
  for (int l = 0; l < L; ++l) {
    node_mlp_kernel<<<ntiles, 256, 0, stream>>>(hin, bnS, bnSS, gmL, btL,
                                                Wm1 + (size_t)l * D * D, bm1 + l * D,
                                                Wr + (size_t)l * D * D, br + l * D,
                                                Rbuf, HRbuf, N);
    agg_kernel<<<2048, 256, 0, stream>>>(row_ptr, csr_src, Rbuf, HRbuf,
                                         Wm2 + (size_t)l * D * D, bm2 + l * D, aconv + l,
                                         hbuf, bnsum + l * D, bnsumsq + l * D, N);
    hin = hbuf;
    bnS = bnsum + l * D;
    bnSS = bnsumsq + l * D;
    gmL = gamma + l * D;
    btL = beta + l * D;
  }

  pool_head_kernel<<<G, 256, 0, stream>>>(hbuf, bnS, bnSS, gmL, btL, batch,
                                          Wh1, bh1, Wh2, bh2, ahead, (float*)d_out, N);
}

// Round 7
// 590.842 us; speedup vs baseline: 1.3779x; 1.0202x over previous
//
#include <hip/hip_runtime.h>
#include <hip/hip_fp16.h>

#define D 64

// ---------------- CSR build ----------------

__global__ __launch_bounds__(256) void hist_kernel(const int* __restrict__ dst,
                                                   int* __restrict__ cnt, int E) {
  int e = blockIdx.x * 256 + threadIdx.x;
  if (e < E) atomicAdd(&cnt[dst[e]], 1);
}

__global__ __launch_bounds__(1024) void scan_partial_kernel(const int* __restrict__ cnt,
                                                            int* __restrict__ bsum, int N) {
  __shared__ int lds[1024];
  int i = blockIdx.x * 1024 + threadIdx.x;
  lds[threadIdx.x] = (i < N) ? cnt[i] : 0;
  __syncthreads();
  for (int off = 512; off > 0; off >>= 1) {
    if (threadIdx.x < off) lds[threadIdx.x] += lds[threadIdx.x + off];
    __syncthreads();
  }
  if (threadIdx.x == 0) bsum[blockIdx.x] = lds[0];
}

// exclusive scan of up to 64 block sums in one wave
__global__ void scan_bsum_kernel(int* __restrict__ bsum, int nb,
                                 int* __restrict__ row_ptr, int N, int E) {
  int tid = threadIdx.x;  // 64 threads
  int o = (tid < nb) ? bsum[tid] : 0;
  int v = o;
  for (int off = 1; off < 64; off <<= 1) {
    int t = __shfl_up(v, off, 64);
    if (tid >= off) v += t;
  }
  if (tid < nb) bsum[tid] = v - o;       // exclusive
  if (tid == 0) row_ptr[N] = E;          // total is always E
}

__global__ __launch_bounds__(1024) void scan_final_kernel(const int* __restrict__ cnt,
                                                          const int* __restrict__ bsum,
                                                          int* __restrict__ row_ptr,
                                                          int* __restrict__ cursor, int N) {
  __shared__ int lds[1024];
  int tid = threadIdx.x;
  int i = blockIdx.x * 1024 + tid;
  int v = (i < N) ? cnt[i] : 0;
  lds[tid] = v;
  __syncthreads();
  for (int off = 1; off < 1024; off <<= 1) {
    int t = (tid >= off) ? lds[tid - off] : 0;
    __syncthreads();
    lds[tid] += t;
    __syncthreads();
  }
  if (i < N) {
    int excl = bsum[blockIdx.x] + lds[tid] - v;
    row_ptr[i] = excl;
    cursor[i] = excl;
  }
}

__global__ __launch_bounds__(256) void scatter_kernel(const int* __restrict__ srcs,
                                                      const int* __restrict__ dst,
                                                      int* __restrict__ cursor,
                                                      int* __restrict__ csr_src, int E) {
  int e = blockIdx.x * 256 + threadIdx.x;
  if (e < E) {
    int p = atomicAdd(&cursor[dst[e]], 1);
    csr_src[p] = srcs[e];
  }
}

// ---------------- node MLP: R = relu(h@Wm1+bm1) in FP16 (row-major), HR = h@Wr+br ----------
// applies previous layer's folded BN inline from raw sums; bnS==null -> identity (layer 0)

__global__ __launch_bounds__(256, 4) void node_mlp_kernel(
    const float* __restrict__ hin, const float* __restrict__ bnS, const float* __restrict__ bnSS,
    const float* __restrict__ gammaL, const float* __restrict__ betaL,
    const float* __restrict__ W1, const float* __restrict__ b1,
    const float* __restrict__ W2, const float* __restrict__ b2,
    __half* __restrict__ Rout, float* __restrict__ HRout, int N) {
  __shared__ float2 w12[D * D];  // [k][c] = {W1[k][c], W2[k][c]}
  __shared__ float hrow[32][D];
  const int tid = threadIdx.x;
  for (int i = tid; i < D * D; i += 256) w12[i] = make_float2(W1[i], W2[i]);
  const int c = tid & 63;
  const int w = tid >> 6;
  float sc = 1.f, sh = 0.f;
  if (bnS) {
    float invN = 1.f / (float)N;
    float mu = bnS[c] * invN;
    float var = bnSS[c] * invN - mu * mu;
    float s = gammaL[c] * rsqrtf(var + 1e-5f);
    sc = s;
    sh = betaL[c] - mu * s;
  }
  const float bb1 = b1[c], bb2 = b2[c];
  const int ntiles = (N + 31) >> 5;
  for (int t = blockIdx.x; t < ntiles; t += gridDim.x) {
    const int base = t * 32;
    __syncthreads();
#pragma unroll
    for (int j = 0; j < 8; ++j) {
      int r = 4 * j + w;
      int row = base + r;
      float v = (row < N) ? hin[(size_t)row * D + c] : 0.f;
      hrow[r][c] = v * sc + sh;
    }
    __syncthreads();
    float a1[8], a2[8];
#pragma unroll
    for (int j = 0; j < 8; ++j) { a1[j] = bb1; a2[j] = bb2; }
    for (int k = 0; k < D; k += 4) {
      const float2 wa = w12[(k + 0) * D + c];
      const float2 wb = w12[(k + 1) * D + c];
      const float2 wc = w12[(k + 2) * D + c];
      const float2 wd = w12[(k + 3) * D + c];
#pragma unroll
      for (int j = 0; j < 8; ++j) {
        const float4 h4 = *(const float4*)&hrow[w * 8 + j][k];
        a1[j] += h4.x * wa.x + h4.y * wb.x + h4.z * wc.x + h4.w * wd.x;
        a2[j] += h4.x * wa.y + h4.y * wb.y + h4.z * wc.y + h4.w * wd.y;
      }
    }
#pragma unroll
    for (int j = 0; j < 8; ++j) {
      int row = base + w * 8 + j;
      if (row < N) {
        Rout[(size_t)row * D + c] = __float2half(fmaxf(a1[j], 0.f));
        HRout[(size_t)row * D + c] = a2[j];
      }
    }
  }
}

// ---------------- aggregation + Wm2 + root add + PReLU + BN partial sums ----------------
// fp16 message table (6.4MB: halved miss traffic, better L2 residency); per node ONE
// coalesced per-lane index load, gather addresses broadcast via v_readlane; next node's
// indices prefetched under current node's gathers+matmul.

__device__ __forceinline__ float lane_bcast(float v, int lane) {
  return __int_as_float(__builtin_amdgcn_readlane(__float_as_int(v), lane));
}
__device__ __forceinline__ int lane_bcast_i(int v, int lane) {
  return __builtin_amdgcn_readlane(v, lane);
}

__global__ __launch_bounds__(256) void agg_kernel(const int* __restrict__ row_ptr,
                                                  const int* __restrict__ csr_src,
                                                  const __half* __restrict__ Rm,
                                                  const float* __restrict__ HRm,
                                                  const float* __restrict__ W2m,
                                                  const float* __restrict__ b2m,
                                                  const float* __restrict__ aconv,
                                                  float* __restrict__ hout,
                                                  float* __restrict__ bnsum,
                                                  float* __restrict__ bnsumsq, int N) {
  __shared__ float w2[D * D];
  __shared__ float red[4][D];
  __shared__ float red2[4][D];
  const int tid = threadIdx.x;
  const int c = tid & 63;
  const int w = tid >> 6;
  for (int i = tid; i < D * D; i += 256) w2[i] = W2m[i];
  const float alpha = *aconv;
  const float bb = b2m[c];
  const int NW = gridDim.x * 4;
  float psum = 0.f, psumsq = 0.f;
  __syncthreads();

  int n = blockIdx.x * 4 + w;
  int e0 = 0, e1 = 0, idx = 0;
  if (n < N) {
    e0 = row_ptr[n];
    e1 = row_ptr[n + 1];
    int m = e1 - e0;
    if (m > 64) m = 64;
    if (m > 0) idx = csr_src[e0 + (c < m ? c : m - 1)];
  }
  while (n < N) {
    // ---- prefetch next node's extents + indices (hidden under gathers/matmul) ----
    const int n2 = n + NW;
    int e0n = 0, e1n = 0, idxn = 0;
    if (n2 < N) {
      e0n = row_ptr[n2];
      e1n = row_ptr[n2 + 1];
      int mn = e1n - e0n;
      if (mn > 64) mn = 64;
      if (mn > 0) idxn = csr_src[e0n + (c < mn ? c : mn - 1)];
    }
    // ---- gather current node (fp16 loads, fp32 accumulate) ----
    const int deg = e1 - e0;
    float acc0 = 0.f, acc1 = 0.f, acc2 = 0.f, acc3 = 0.f;
    float acc4 = 0.f, acc5 = 0.f, acc6 = 0.f, acc7 = 0.f;
    int kb = 0;
    int curidx = idx;
    while (kb < deg) {
      int m = deg - kb;
      if (m > 64) m = 64;
      if (kb > 0) curidx = csr_src[e0 + kb + (c < m ? c : m - 1)];
      int j = 0;
      for (; j + 7 < m; j += 8) {
        const int s0 = lane_bcast_i(curidx, j + 0);
        const int s1 = lane_bcast_i(curidx, j + 1);
        const int s2 = lane_bcast_i(curidx, j + 2);
        const int s3 = lane_bcast_i(curidx, j + 3);
        const int s4 = lane_bcast_i(curidx, j + 4);
        const int s5 = lane_bcast_i(curidx, j + 5);
        const int s6 = lane_bcast_i(curidx, j + 6);
        const int s7 = lane_bcast_i(curidx, j + 7);
        acc0 += __half2float(Rm[(size_t)s0 * D + c]);
        acc1 += __half2float(Rm[(size_t)s1 * D + c]);
        acc2 += __half2float(Rm[(size_t)s2 * D + c]);
        acc3 += __half2float(Rm[(size_t)s3 * D + c]);
        acc4 += __half2float(Rm[(size_t)s4 * D + c]);
        acc5 += __half2float(Rm[(size_t)s5 * D + c]);
        acc6 += __half2float(Rm[(size_t)s6 * D + c]);
        acc7 += __half2float(Rm[(size_t)s7 * D + c]);
      }
      for (; j < m; ++j) acc0 += __half2float(Rm[(size_t)lane_bcast_i(curidx, j) * D + c]);
      kb += m;
    }
    const float aggv = ((acc0 + acc1) + (acc2 + acc3)) + ((acc4 + acc5) + (acc6 + acc7));
    // ---- Wm2 matmul + root + PReLU + BN ----
    const float degf = (float)deg;
    float o0 = bb * degf + HRm[(size_t)n * D + c];
    float o1 = 0.f, o2 = 0.f, o3 = 0.f;
#pragma unroll
    for (int kk = 0; kk < D; kk += 4) {
      o0 += lane_bcast(aggv, kk + 0) * w2[(kk + 0) * D + c];
      o1 += lane_bcast(aggv, kk + 1) * w2[(kk + 1) * D + c];
      o2 += lane_bcast(aggv, kk + 2) * w2[(kk + 2) * D + c];
      o3 += lane_bcast(aggv, kk + 3) * w2[(kk + 3) * D + c];
    }
    const float o = (o0 + o1) + (o2 + o3);
    const float h2 = (o >= 0.f) ? o : alpha * o;
    hout[(size_t)n * D + c] = h2;
    psum += h2;
    psumsq += h2 * h2;
    // ---- advance ----
    n = n2;
    e0 = e0n;
    e1 = e1n;
    idx = idxn;
  }
  red[w][c] = psum;
  red2[w][c] = psumsq;
  __syncthreads();
  if (w == 0) {
    float s = red[0][c] + red[1][c] + red[2][c] + red[3][c];
    float ss = red2[0][c] + red2[1][c] + red2[2][c] + red2[3][c];
    atomicAdd(&bnsum[c], s);
    atomicAdd(&bnsumsq[c], ss);
  }
}

// ---------------- pooling (sorted batch, binary search) + MLP head ----------------

__global__ __launch_bounds__(256) void pool_head_kernel(
    const float* __restrict__ h, const float* __restrict__ bnS, const float* __restrict__ bnSS,
    const float* __restrict__ gammaL, const float* __restrict__ betaL,
    const int* __restrict__ batch, const float* __restrict__ Wh1, const float* __restrict__ bh1,
    const float* __restrict__ Wh2, const float* __restrict__ bh2,
    const float* __restrict__ ahead, float* __restrict__ out, int N) {
  const int g = blockIdx.x;
  const int tid = threadIdx.x;
  const int c = tid & 63;
  const int w = tid >> 6;
  float sc, sh;
  {
    float invN = 1.f / (float)N;
    float mu = bnS[c] * invN;
    float var = bnSS[c] * invN - mu * mu;
    float s = gammaL[c] * rsqrtf(var + 1e-5f);
    sc = s;
    sh = betaL[c] - mu * s;
  }
  int s0, s1;
  {
    int lo = 0, hi = N;
    while (lo < hi) { int mid = (lo + hi) >> 1; if (batch[mid] < g) lo = mid + 1; else hi = mid; }
    s0 = lo;
    lo = s0; hi = N;
    while (lo < hi) { int mid = (lo + hi) >> 1; if (batch[mid] < g + 1) lo = mid + 1; else hi = mid; }
    s1 = lo;
  }
  float sum = 0.f;
  for (int r = s0 + w; r < s1; r += 4) sum += h[(size_t)r * D + c] * sc + sh;
  __shared__ float red[4][D];
  __shared__ float mean[D];
  red[w][c] = sum;
  __syncthreads();
  if (tid < D) {
    float cnt = (float)(s1 - s0);
    mean[c] = (red[0][c] + red[1][c] + red[2][c] + red[3][c]) / fmaxf(cnt, 1.0f);
  }
  __syncthreads();
  if (tid < D) {
    int j = tid;
    float a = bh1[j];
#pragma unroll
    for (int k = 0; k < D; ++k) a += mean[k] * Wh1[k * D + j];
    float al = *ahead;
    float v = (a >= 0.f) ? a : al * a;
    float pval = v * Wh2[j];
    for (int off = 32; off > 0; off >>= 1) pval += __shfl_down(pval, off, 64);
    if (j == 0) out[g] = pval + bh2[0];
  }
}

// ---------------- host ----------------

extern "C" void kernel_launch(void* const* d_in, const int* in_sizes, int n_in,
                              void* d_out, int out_size, void* d_ws, size_t ws_size,
                              hipStream_t stream) {
  const float* x = (const float*)d_in[0];
  const int* ei = (const int*)d_in[1];
  const int* batch = (const int*)d_in[2];
  const float* Wm1 = (const float*)d_in[3];
  const float* bm1 = (const float*)d_in[4];
  const float* Wm2 = (const float*)d_in[5];
  const float* bm2 = (const float*)d_in[6];
  const float* Wr = (const float*)d_in[7];
  const float* br = (const float*)d_in[8];
  const float* aconv = (const float*)d_in[9];
  const float* gamma = (const float*)d_in[10];
  const float* beta = (const float*)d_in[11];
  const float* Wh1 = (const float*)d_in[12];
  const float* bh1 = (const float*)d_in[13];
  const float* Wh2 = (const float*)d_in[14];
  const float* bh2 = (const float*)d_in[15];
  const float* ahead = (const float*)d_in[16];

  const int N = in_sizes[0] / D;
  const int E = in_sizes[1] / 2;
  const int L = in_sizes[3] / (D * D);
  const int G = out_size;

  const int* srcs = ei;
  const int* dsts = ei + E;

  char* p = (char*)d_ws;
  auto alloc = [&](size_t bytes) {
    char* r = p;
    p += (bytes + 255) & ~(size_t)255;
    return r;
  };
  int* row_ptr = (int*)alloc((size_t)(N + 1) * 4);
  int* cursor = (int*)alloc((size_t)N * 4);
  int* bsum = (int*)alloc(64 * 4);
  int* csr_src = (int*)alloc((size_t)E * 4);
  __half* Rbuf = (__half*)alloc((size_t)N * D * 2);   // fp16 message table (6.4 MB)
  float* HRbuf = (float*)alloc((size_t)N * D * 4);
  float* hbuf = (float*)alloc((size_t)N * D * 4);
  float* bnsum = (float*)alloc((size_t)L * D * 4 * 2);
  float* bnsumsq = bnsum + (size_t)L * D;

  hipMemsetAsync(row_ptr, 0, (size_t)((char*)(cursor + N) - (char*)row_ptr), stream);
  hipMemsetAsync(bnsum, 0, (size_t)L * D * 4 * 2, stream);

  // CSR build
  const int nb = (N + 1023) / 1024;
  hist_kernel<<<(E + 255) / 256, 256, 0, stream>>>(dsts, cursor, E);
  scan_partial_kernel<<<nb, 1024, 0, stream>>>(cursor, bsum, N);
  scan_bsum_kernel<<<1, 64, 0, stream>>>(bsum, nb, row_ptr, N, E);
  scan_final_kernel<<<nb, 1024, 0, stream>>>(cursor, bsum, row_ptr, cursor, N);
  scatter_kernel<<<(E + 255) / 256, 256, 0, stream>>>(srcs, dsts, cursor, csr_src, E);

  const int ntiles = (N + 31) / 32;

  const float* hin = x;
  const float* bnS = nullptr;
  const float* bnSS = nullptr;
  const float* gmL = nullptr;
  const float* btL = nullptr;
  for (int l = 0; l < L; ++l) {
    node_mlp_kernel<<<ntiles, 256, 0, stream>>>(hin, bnS, bnSS, gmL, btL,
                                                Wm1 + (size_t)l * D * D, bm1 + l * D,
                                                Wr + (size_t)l * D * D, br + l * D,
                                                Rbuf, HRbuf, N);
    agg_kernel<<<2048, 256, 0, stream>>>(row_ptr, csr_src, Rbuf, HRbuf,
                                         Wm2 + (size_t)l * D * D, bm2 + l * D, aconv + l,
                                         hbuf, bnsum + l * D, bnsumsq + l * D, N);
    hin = hbuf;
    bnS = bnsum + l * D;
    bnSS = bnsumsq + l * D;
    gmL = gamma + l * D;
    btL = beta + l * D;
  }

  pool_head_kernel<<<G, 256, 0, stream>>>(hbuf, bnS, bnSS, gmL, btL, batch,
                                          Wh1, bh1, Wh2, bh2, ahead, (float*)d_out, N);
}

// Round 8
// 590.766 us; speedup vs baseline: 1.3781x; 1.0001x over previous
//
#include <hip/hip_runtime.h>
#include <hip/hip_fp16.h>

#define D 64

// ---------------- CSR build ----------------

__global__ __launch_bounds__(256) void hist_kernel(const int* __restrict__ dst,
                                                   int* __restrict__ cnt, int E) {
  int e = blockIdx.x * 256 + threadIdx.x;
  if (e < E) atomicAdd(&cnt[dst[e]], 1);
}

__global__ __launch_bounds__(1024) void scan_partial_kernel(const int* __restrict__ cnt,
                                                            int* __restrict__ bsum, int N) {
  __shared__ int lds[1024];
  int i = blockIdx.x * 1024 + threadIdx.x;
  lds[threadIdx.x] = (i < N) ? cnt[i] : 0;
  __syncthreads();
  for (int off = 512; off > 0; off >>= 1) {
    if (threadIdx.x < off) lds[threadIdx.x] += lds[threadIdx.x + off];
    __syncthreads();
  }
  if (threadIdx.x == 0) bsum[blockIdx.x] = lds[0];
}

// exclusive scan of up to 64 block sums in one wave
__global__ void scan_bsum_kernel(int* __restrict__ bsum, int nb,
                                 int* __restrict__ row_ptr, int N, int E) {
  int tid = threadIdx.x;  // 64 threads
  int o = (tid < nb) ? bsum[tid] : 0;
  int v = o;
  for (int off = 1; off < 64; off <<= 1) {
    int t = __shfl_up(v, off, 64);
    if (tid >= off) v += t;
  }
  if (tid < nb) bsum[tid] = v - o;       // exclusive
  if (tid == 0) row_ptr[N] = E;          // total is always E
}

__global__ __launch_bounds__(1024) void scan_final_kernel(const int* __restrict__ cnt,
                                                          const int* __restrict__ bsum,
                                                          int* __restrict__ row_ptr,
                                                          int* __restrict__ cursor, int N) {
  __shared__ int lds[1024];
  int tid = threadIdx.x;
  int i = blockIdx.x * 1024 + tid;
  int v = (i < N) ? cnt[i] : 0;
  lds[tid] = v;
  __syncthreads();
  for (int off = 1; off < 1024; off <<= 1) {
    int t = (tid >= off) ? lds[tid - off] : 0;
    __syncthreads();
    lds[tid] += t;
    __syncthreads();
  }
  if (i < N) {
    int excl = bsum[blockIdx.x] + lds[tid] - v;
    row_ptr[i] = excl;
    cursor[i] = excl;
  }
}

__global__ __launch_bounds__(256) void scatter_kernel(const int* __restrict__ srcs,
                                                      const int* __restrict__ dst,
                                                      int* __restrict__ cursor,
                                                      int* __restrict__ csr_src, int E) {
  int e = blockIdx.x * 256 + threadIdx.x;
  if (e < E) {
    int p = atomicAdd(&cursor[dst[e]], 1);
    csr_src[p] = srcs[e];
  }
}

// ---------------- node MLP: R = relu(h@Wm1+bm1) in FP16 (row-major), HR = h@Wr+br ----------
// applies previous layer's folded BN inline from raw sums; bnS==null -> identity (layer 0)

__global__ __launch_bounds__(256, 4) void node_mlp_kernel(
    const float* __restrict__ hin, const float* __restrict__ bnS, const float* __restrict__ bnSS,
    const float* __restrict__ gammaL, const float* __restrict__ betaL,
    const float* __restrict__ W1, const float* __restrict__ b1,
    const float* __restrict__ W2, const float* __restrict__ b2,
    __half* __restrict__ Rout, float* __restrict__ HRout, int N) {
  __shared__ float2 w12[D * D];  // [k][c] = {W1[k][c], W2[k][c]}
  __shared__ float hrow[32][D];
  const int tid = threadIdx.x;
  for (int i = tid; i < D * D; i += 256) w12[i] = make_float2(W1[i], W2[i]);
  const int c = tid & 63;
  const int w = tid >> 6;
  float sc = 1.f, sh = 0.f;
  if (bnS) {
    float invN = 1.f / (float)N;
    float mu = bnS[c] * invN;
    float var = bnSS[c] * invN - mu * mu;
    float s = gammaL[c] * rsqrtf(var + 1e-5f);
    sc = s;
    sh = betaL[c] - mu * s;
  }
  const float bb1 = b1[c], bb2 = b2[c];
  const int ntiles = (N + 31) >> 5;
  for (int t = blockIdx.x; t < ntiles; t += gridDim.x) {
    const int base = t * 32;
    __syncthreads();
#pragma unroll
    for (int j = 0; j < 8; ++j) {
      int r = 4 * j + w;
      int row = base + r;
      float v = (row < N) ? hin[(size_t)row * D + c] : 0.f;
      hrow[r][c] = v * sc + sh;
    }
    __syncthreads();
    float a1[8], a2[8];
#pragma unroll
    for (int j = 0; j < 8; ++j) { a1[j] = bb1; a2[j] = bb2; }
    for (int k = 0; k < D; k += 4) {
      const float2 wa = w12[(k + 0) * D + c];
      const float2 wb = w12[(k + 1) * D + c];
      const float2 wc = w12[(k + 2) * D + c];
      const float2 wd = w12[(k + 3) * D + c];
#pragma unroll
      for (int j = 0; j < 8; ++j) {
        const float4 h4 = *(const float4*)&hrow[w * 8 + j][k];
        a1[j] += h4.x * wa.x + h4.y * wb.x + h4.z * wc.x + h4.w * wd.x;
        a2[j] += h4.x * wa.y + h4.y * wb.y + h4.z * wc.y + h4.w * wd.y;
      }
    }
#pragma unroll
    for (int j = 0; j < 8; ++j) {
      int row = base + w * 8 + j;
      if (row < N) {
        Rout[(size_t)row * D + c] = __float2half(fmaxf(a1[j], 0.f));
        HRout[(size_t)row * D + c] = a2[j];
      }
    }
  }
}

// ---------------- aggregation + Wm2 + root add + PReLU + BN partial sums ----------------
// 4 EDGES PER GATHER INSTRUCTION: fp16 rows are 128B, so 16 lanes x ushort4 cover one row;
// lane l serves edge-slot (l>>4), channel-quad (l&15). One __shfl broadcasts 4 indices.
// Cross-slot reduce = 8 shfl_xor per node. Wm2 matmul via readlane on float4 components.

__device__ __forceinline__ float lane_bcast(float v, int lane) {
  return __int_as_float(__builtin_amdgcn_readlane(__float_as_int(v), lane));
}
__device__ __forceinline__ int lane_bcast_i(int v, int lane) {
  return __builtin_amdgcn_readlane(v, lane);
}

__global__ __launch_bounds__(256) void agg_kernel(const int* __restrict__ row_ptr,
                                                  const int* __restrict__ csr_src,
                                                  const __half* __restrict__ Rm,
                                                  const float* __restrict__ HRm,
                                                  const float* __restrict__ W2m,
                                                  const float* __restrict__ b2m,
                                                  const float* __restrict__ aconv,
                                                  float* __restrict__ hout,
                                                  float* __restrict__ bnsum,
                                                  float* __restrict__ bnsumsq, int N) {
  __shared__ float w2[D * D];
  __shared__ float red[4][D];
  __shared__ float red2[4][D];
  const int tid = threadIdx.x;
  const int c = tid & 63;
  const int w = tid >> 6;
  const int q = c & 15;    // channel quad: channels 4q..4q+3
  const int eg = c >> 4;   // edge slot 0..3
  for (int i = tid; i < D * D; i += 256) w2[i] = W2m[i];
  const float alpha = *aconv;
  const float bb = b2m[c];
  const int NW = gridDim.x * 4;
  float psum = 0.f, psumsq = 0.f;
  __syncthreads();

  int n = blockIdx.x * 4 + w;
  int e0 = 0, e1 = 0, idx = 0;
  if (n < N) {
    e0 = row_ptr[n];
    e1 = row_ptr[n + 1];
    int m = e1 - e0;
    if (m > 64) m = 64;
    if (m > 0) idx = csr_src[e0 + (c < m ? c : m - 1)];
  }
  while (n < N) {
    // ---- prefetch next node's extents + indices (hidden under gathers/matmul) ----
    const int n2 = n + NW;
    int e0n = 0, e1n = 0, idxn = 0;
    if (n2 < N) {
      e0n = row_ptr[n2];
      e1n = row_ptr[n2 + 1];
      int mn = e1n - e0n;
      if (mn > 64) mn = 64;
      if (mn > 0) idxn = csr_src[e0n + (c < mn ? c : mn - 1)];
    }
    // ---- gather current node: 4 edges per instruction ----
    const int deg = e1 - e0;
    float acc0 = 0.f, acc1 = 0.f, acc2 = 0.f, acc3 = 0.f;
    int kb = 0;
    int curidx = idx;
    while (kb < deg) {
      int m = deg - kb;
      if (m > 64) m = 64;
      if (kb > 0) curidx = csr_src[e0 + kb + (c < m ? c : m - 1)];
      int j = 0;
      for (; j + 3 < m; j += 4) {
        const int s = __shfl(curidx, j + eg, 64);
        const uint2 rv = *(const uint2*)(Rm + (size_t)s * D + (q << 2));
        const float2 f01 = __half22float2(*(const __half2*)&rv.x);
        const float2 f23 = __half22float2(*(const __half2*)&rv.y);
        acc0 += f01.x;
        acc1 += f01.y;
        acc2 += f23.x;
        acc3 += f23.y;
      }
      for (; j < m; ++j) {  // tail: single edge on slot 0
        const int s = lane_bcast_i(curidx, j);
        if (eg == 0) {
          const uint2 rv = *(const uint2*)(Rm + (size_t)s * D + (q << 2));
          const float2 f01 = __half22float2(*(const __half2*)&rv.x);
          const float2 f23 = __half22float2(*(const __half2*)&rv.y);
          acc0 += f01.x;
          acc1 += f01.y;
          acc2 += f23.x;
          acc3 += f23.y;
        }
      }
      kb += m;
    }
    // reduce across the 4 edge slots (xor 16 then 32): all lanes end with quad-q sums
    acc0 += __shfl_xor(acc0, 16, 64);
    acc1 += __shfl_xor(acc1, 16, 64);
    acc2 += __shfl_xor(acc2, 16, 64);
    acc3 += __shfl_xor(acc3, 16, 64);
    acc0 += __shfl_xor(acc0, 32, 64);
    acc1 += __shfl_xor(acc1, 32, 64);
    acc2 += __shfl_xor(acc2, 32, 64);
    acc3 += __shfl_xor(acc3, 32, 64);
    // ---- Wm2 matmul + root + PReLU + BN ----
    const float degf = (float)deg;
    float o0 = bb * degf + HRm[(size_t)n * D + c];
    float o1 = 0.f, o2 = 0.f, o3 = 0.f;
#pragma unroll
    for (int kk = 0; kk < D; kk += 4) {
      const int src = kk >> 2;  // lane holding channels kk..kk+3
      o0 += lane_bcast(acc0, src) * w2[(kk + 0) * D + c];
      o1 += lane_bcast(acc1, src) * w2[(kk + 1) * D + c];
      o2 += lane_bcast(acc2, src) * w2[(kk + 2) * D + c];
      o3 += lane_bcast(acc3, src) * w2[(kk + 3) * D + c];
    }
    const float o = (o0 + o1) + (o2 + o3);
    const float h2 = (o >= 0.f) ? o : alpha * o;
    hout[(size_t)n * D + c] = h2;
    psum += h2;
    psumsq += h2 * h2;
    // ---- advance ----
    n = n2;
    e0 = e0n;
    e1 = e1n;
    idx = idxn;
  }
  red[w][c] = psum;
  red2[w][c] = psumsq;
  __syncthreads();
  if (w == 0) {
    float s = red[0][c] + red[1][c] + red[2][c] + red[3][c];
    float ss = red2[0][c] + red2[1][c] + red2[2][c] + red2[3][c];
    atomicAdd(&bnsum[c], s);
    atomicAdd(&bnsumsq[c], ss);
  }
}

// ---------------- pooling (sorted batch, binary search) + MLP head ----------------

__global__ __launch_bounds__(256) void pool_head_kernel(
    const float* __restrict__ h, const float* __restrict__ bnS, const float* __restrict__ bnSS,
    const float* __restrict__ gammaL, const float* __restrict__ betaL,
    const int* __restrict__ batch, const float* __restrict__ Wh1, const float* __restrict__ bh1,
    const float* __restrict__ Wh2, const float* __restrict__ bh2,
    const float* __restrict__ ahead, float* __restrict__ out, int N) {
  const int g = blockIdx.x;
  const int tid = threadIdx.x;
  const int c = tid & 63;
  const int w = tid >> 6;
  float sc, sh;
  {
    float invN = 1.f / (float)N;
    float mu = bnS[c] * invN;
    float var = bnSS[c] * invN - mu * mu;
    float s = gammaL[c] * rsqrtf(var + 1e-5f);
    sc = s;
    sh = betaL[c] - mu * s;
  }
  int s0, s1;
  {
    int lo = 0, hi = N;
    while (lo < hi) { int mid = (lo + hi) >> 1; if (batch[mid] < g) lo = mid + 1; else hi = mid; }
    s0 = lo;
    lo = s0; hi = N;
    while (lo < hi) { int mid = (lo + hi) >> 1; if (batch[mid] < g + 1) lo = mid + 1; else hi = mid; }
    s1 = lo;
  }
  float sum = 0.f;
  for (int r = s0 + w; r < s1; r += 4) sum += h[(size_t)r * D + c] * sc + sh;
  __shared__ float red[4][D];
  __shared__ float mean[D];
  red[w][c] = sum;
  __syncthreads();
  if (tid < D) {
    float cnt = (float)(s1 - s0);
    mean[c] = (red[0][c] + red[1][c] + red[2][c] + red[3][c]) / fmaxf(cnt, 1.0f);
  }
  __syncthreads();
  if (tid < D) {
    int j = tid;
    float a = bh1[j];
#pragma unroll
    for (int k = 0; k < D; ++k) a += mean[k] * Wh1[k * D + j];
    float al = *ahead;
    float v = (a >= 0.f) ? a : al * a;
    float pval = v * Wh2[j];
    for (int off = 32; off > 0; off >>= 1) pval += __shfl_down(pval, off, 64);
    if (j == 0) out[g] = pval + bh2[0];
  }
}

// ---------------- host ----------------

extern "C" void kernel_launch(void* const* d_in, const int* in_sizes, int n_in,
                              void* d_out, int out_size, void* d_ws, size_t ws_size,
                              hipStream_t stream) {
  const float* x = (const float*)d_in[0];
  const int* ei = (const int*)d_in[1];
  const int* batch = (const int*)d_in[2];
  const float* Wm1 = (const float*)d_in[3];
  const float* bm1 = (const float*)d_in[4];
  const float* Wm2 = (const float*)d_in[5];
  const float* bm2 = (const float*)d_in[6];
  const float* Wr = (const float*)d_in[7];
  const float* br = (const float*)d_in[8];
  const float* aconv = (const float*)d_in[9];
  const float* gamma = (const float*)d_in[10];
  const float* beta = (const float*)d_in[11];
  const float* Wh1 = (const float*)d_in[12];
  const float* bh1 = (const float*)d_in[13];
  const float* Wh2 = (const float*)d_in[14];
  const float* bh2 = (const float*)d_in[15];
  const float* ahead = (const float*)d_in[16];

  const int N = in_sizes[0] / D;
  const int E = in_sizes[1] / 2;
  const int L = in_sizes[3] / (D * D);
  const int G = out_size;

  const int* srcs = ei;
  const int* dsts = ei + E;

  char* p = (char*)d_ws;
  auto alloc = [&](size_t bytes) {
    char* r = p;
    p += (bytes + 255) & ~(size_t)255;
    return r;
  };
  int* row_ptr = (int*)alloc((size_t)(N + 1) * 4);
  int* cursor = (int*)alloc((size_t)N * 4);
  int* bsum = (int*)alloc(64 * 4);
  int* csr_src = (int*)alloc((size_t)E * 4);
  __half* Rbuf = (__half*)alloc((size_t)N * D * 2);   // fp16 message table (6.4 MB)
  float* HRbuf = (float*)alloc((size_t)N * D * 4);
  float* hbuf = (float*)alloc((size_t)N * D * 4);
  float* bnsum = (float*)alloc((size_t)L * D * 4 * 2);
  float* bnsumsq = bnsum + (size_t)L * D;

  hipMemsetAsync(row_ptr, 0, (size_t)((char*)(cursor + N) - (char*)row_ptr), stream);
  hipMemsetAsync(bnsum, 0, (size_t)L * D * 4 * 2, stream);

  // CSR build
  const int nb = (N + 1023) / 1024;
  hist_kernel<<<(E + 255) / 256, 256, 0, stream>>>(dsts, cursor, E);
  scan_partial_kernel<<<nb, 1024, 0, stream>>>(cursor, bsum, N);
  scan_bsum_kernel<<<1, 64, 0, stream>>>(bsum, nb, row_ptr, N, E);
  scan_final_kernel<<<nb, 1024, 0, stream>>>(cursor, bsum, row_ptr, cursor, N);
  scatter_kernel<<<(E + 255) / 256, 256, 0, stream>>>(srcs, dsts, cursor, csr_src, E);

  const int ntiles = (N + 31) / 32;

  const float* hin = x;
  const float* bnS = nullptr;
  const float* bnSS = nullptr;
  const float* gmL = nullptr;
  const float* btL = nullptr;
  for (int l = 0; l < L; ++l) {
    node_mlp_kernel<<<ntiles, 256, 0, stream>>>(hin, bnS, bnSS, gmL, btL,
                                                Wm1 + (size_t)l * D * D, bm1 + l * D,
                                                Wr + (size_t)l * D * D, br + l * D,
                                                Rbuf, HRbuf, N);
    agg_kernel<<<2048, 256, 0, stream>>>(row_ptr, csr_src, Rbuf, HRbuf,
                                         Wm2 + (size_t)l * D * D, bm2 + l * D, aconv + l,
                                         hbuf, bnsum + l * D, bnsumsq + l * D, N);
    hin = hbuf;
    bnS = bnsum + l * D;
    bnSS = bnsumsq + l * D;
    gmL = gamma + l * D;
    btL = beta + l * D;
  }

  pool_head_kernel<<<G, 256, 0, stream>>>(hbuf, bnS, bnSS, gmL, btL, batch,
                                          Wh1, bh1, Wh2, bh2, ahead, (float*)d_out, N);
}